// Round 1
// baseline (711.212 us; speedup 1.0000x reference)
//
#include <hip/hip_runtime.h>

#define NN   100000
#define TL   128
#define OC   5
#define KW   7
#define ST   3
#define CL   41          // (128-7)/3+1
#define FLAT 205         // 5*41
#define EMB  32
#define HID  16
#define NE   3200000
#define NB_SCAN 391      // ceil(NN/256)

// ===========================================================================
// Precompute combined weight Wc = g1w1 @ fc_w  ([16 x 205], stored transposed
// j-major as wcT[j*16+l]) and bc = g1w1 @ fc_b ([16]).  One block, trivial.
// ===========================================================================
__global__ __launch_bounds__(256) void k_prep(
    const float* __restrict__ g1w1, const float* __restrict__ fc_w,
    const float* __restrict__ fc_b,
    float* __restrict__ wcT, float* __restrict__ bc)
{
    int tid = threadIdx.x;
    for (int idx = tid; idx < FLAT * HID; idx += 256) {
        int l = idx & 15;
        int j = idx >> 4;
        float s = 0.f;
        #pragma unroll
        for (int m = 0; m < EMB; ++m)
            s = fmaf(g1w1[l * EMB + m], fc_w[m * FLAT + j], s);
        wcT[j * HID + l] = s;
    }
    if (tid < HID) {
        float s = 0.f;
        #pragma unroll
        for (int m = 0; m < EMB; ++m)
            s = fmaf(g1w1[tid * EMB + m], fc_b[m], s);
        bc[tid] = s;
    }
}

// ===========================================================================
// Fused Conv1d+ReLU+FC(+g1w1): 32-node tile per block.
//   stage x rows in LDS (pad 129)  -> conv into s_h[o][n] (stride 32)
//   -> FC against wcT -> p1[n][l].
// Eliminates the 82 MB Ht buffer (164 MB of HBM round-trip).
// Bank checks: conv read bank=(n + t*3+k)%32 (2-way free); s_h write bank=n
// (2-way free); FC read s_h[j*32+n2] 4 distinct banks + broadcast (free).
// LDS = 32*129*4 + 205*32*4 = 42.75 KB -> 3 blocks/CU.
// ===========================================================================
__global__ __launch_bounds__(256) void k_convfc(
    const float* __restrict__ x,
    const float* __restrict__ conv_w, const float* __restrict__ conv_b,
    const float* __restrict__ wcT,   const float* __restrict__ bc,
    float* __restrict__ p1)
{
    __shared__ float s_x[32 * 129];
    __shared__ float s_h[FLAT * 32];
    const int tid = threadIdx.x;
    const long long n0 = (long long)blockIdx.x * 32;   // NN = 32*3125 exact

    // stage 32 x-rows: 1024 float4 loads, coalesced
    const float4* xv = (const float4*)(x + n0 * TL);
    #pragma unroll
    for (int c = 0; c < 4; ++c) {
        int f4  = c * 256 + tid;      // 0..1023
        int row = f4 >> 5;            // 32 float4 per 128-float row
        int c4  = f4 & 31;
        float4 v = xv[f4];
        float* d = s_x + row * 129 + c4 * 4;
        d[0] = v.x; d[1] = v.y; d[2] = v.z; d[3] = v.w;
    }
    __syncthreads();

    // conv: 205*32 outputs; o = idx>>5 near-wave-uniform -> w/b scalar-ish
    for (int idx = tid; idx < FLAT * 32; idx += 256) {
        int n = idx & 31;
        int o = idx >> 5;
        int c = o / CL;
        int t = o - c * CL;
        float acc = conv_b[c];
        const float* wr = conv_w + c * KW;
        const float* xr = s_x + n * 129 + t * ST;
        #pragma unroll
        for (int k = 0; k < KW; ++k)
            acc = fmaf(xr[k], wr[k], acc);
        s_h[o * 32 + n] = fmaxf(acc, 0.f);
    }
    __syncthreads();

    // FC: 32 nodes x 16 outputs; lane handles (l, n2) and (l, n2+16)
    const int l  = tid & 15;
    const int n2 = tid >> 4;          // 0..15
    float a0 = bc[l];
    float a1 = a0;
    #pragma unroll 5
    for (int j = 0; j < FLAT; ++j) {
        float w = wcT[j * HID + l];
        a0 = fmaf(s_h[j * 32 + n2],      w, a0);
        a1 = fmaf(s_h[j * 32 + n2 + 16], w, a1);
    }
    p1[(n0 + n2)      * HID + l] = a0;   // coalesced 64B per 16-lane group
    p1[(n0 + n2 + 16) * HID + l] = a1;
}

// ===========================================================================
// CSR build (once, reused by both GIN layers)
// ===========================================================================
__global__ __launch_bounds__(256) void k_hist(
    const int* __restrict__ ei, int* __restrict__ deg)
{
    int e = blockIdx.x * 256 + threadIdx.x;       // grid exact: NE/256
    atomicAdd(deg + ei[NE + e], 1);
}

__global__ __launch_bounds__(256) void k_scan1(
    const int* __restrict__ deg, int* __restrict__ off,
    int* __restrict__ psum)
{
    __shared__ int s[256];
    int i = blockIdx.x * 256 + threadIdx.x;
    int v = (i < NN) ? deg[i] : 0;
    s[threadIdx.x] = v;
    __syncthreads();
    #pragma unroll
    for (int d = 1; d < 256; d <<= 1) {
        int t = (threadIdx.x >= d) ? s[threadIdx.x - d] : 0;
        __syncthreads();
        s[threadIdx.x] += t;
        __syncthreads();
    }
    if (i < NN) off[i] = s[threadIdx.x] - v;      // exclusive (local)
    if (threadIdx.x == 255) psum[blockIdx.x] = s[255];
}

__global__ __launch_bounds__(512) void k_scan2(
    int* __restrict__ psum, int* __restrict__ off)
{
    __shared__ int s[512];
    int tid = threadIdx.x;
    int v = (tid < NB_SCAN) ? psum[tid] : 0;
    s[tid] = v;
    __syncthreads();
    #pragma unroll
    for (int d = 1; d < 512; d <<= 1) {
        int t = (tid >= d) ? s[tid - d] : 0;
        __syncthreads();
        s[tid] += t;
        __syncthreads();
    }
    if (tid < NB_SCAN) psum[tid] = s[tid] - v;    // exclusive block base
    if (tid == NB_SCAN - 1) off[NN] = s[tid];     // total = NE
}

__global__ __launch_bounds__(256) void k_scan3(
    int* __restrict__ off, const int* __restrict__ psum,
    int* __restrict__ cur)
{
    int i = blockIdx.x * 256 + threadIdx.x;
    if (i < NN) {
        int v = off[i] + psum[blockIdx.x];
        off[i] = v;
        cur[i] = v;
    }
}

__global__ __launch_bounds__(256) void k_fill(
    const int* __restrict__ ei, int* __restrict__ cur,
    int* __restrict__ csr)
{
    int e = blockIdx.x * 256 + threadIdx.x;       // grid exact: NE/256
    int src = ei[e];
    int dst = ei[NE + e];
    int pos = atomicAdd(cur + dst, 1);
    csr[pos] = src;
}

// ===========================================================================
// Atomic-free aggregation: 4 lanes per node, float4 per lane, sum in-edges.
// Reads: 64B/edge from 6.4MB L2/L3-resident p.  Writes: coalesced 6.4MB.
// ===========================================================================
__global__ __launch_bounds__(256) void k_gather(
    const float* __restrict__ p, const int* __restrict__ off,
    const int* __restrict__ csr, float* __restrict__ agg)
{
    const int t  = blockIdx.x * 256 + threadIdx.x;
    const int g  = t >> 2;
    const int l4 = t & 3;
    if (g >= NN) return;
    const float4* pv = (const float4*)p;
    int j = off[g];
    const int e = off[g + 1];
    float4 acc = make_float4(0.f, 0.f, 0.f, 0.f);
    for (; j + 1 < e; j += 2) {
        int s0 = csr[j], s1 = csr[j + 1];
        float4 a = pv[(size_t)s0 * 4 + l4];
        float4 b = pv[(size_t)s1 * 4 + l4];
        acc.x += a.x + b.x; acc.y += a.y + b.y;
        acc.z += a.z + b.z; acc.w += a.w + b.w;
    }
    if (j < e) {
        float4 a = pv[(size_t)csr[j] * 4 + l4];
        acc.x += a.x; acc.y += a.y; acc.z += a.z; acc.w += a.w;
    }
    ((float4*)agg)[(size_t)g * 4 + l4] = acc;
}

// ===========================================================================
// FALLBACK PATH kernels (workspace too small): round-1 k_embed + atomic scatter
// ===========================================================================
__global__ __launch_bounds__(256) void k_embed(
    const float* __restrict__ x,
    const float* __restrict__ conv_w, const float* __restrict__ conv_b,
    const float* __restrict__ fc_w,   const float* __restrict__ fc_b,
    const float* __restrict__ g1w1,
    float* __restrict__ p1)
{
    __shared__ float s_x[4][TL];
    __shared__ float s_h[4][FLAT + 3];
    __shared__ float s_e[4][EMB];

    const int w    = threadIdx.x >> 6;
    const int lane = threadIdx.x & 63;
    const int node = blockIdx.x * 4 + w;

    const float2* xr = (const float2*)(x + (size_t)node * TL);
    float2 v = xr[lane];
    s_x[w][lane * 2 + 0] = v.x;
    s_x[w][lane * 2 + 1] = v.y;
    __syncthreads();

    for (int o = lane; o < FLAT; o += 64) {
        int c = o / CL;
        int t = o - c * CL;
        float acc = conv_b[c];
        #pragma unroll
        for (int k = 0; k < KW; ++k)
            acc += s_x[w][t * ST + k] * conv_w[c * KW + k];
        s_h[w][o] = fmaxf(acc, 0.f);
    }
    __syncthreads();

    if (lane < EMB) {
        float acc = fc_b[lane];
        const float* wr = fc_w + lane * FLAT;
        for (int j = 0; j < FLAT; ++j)
            acc += s_h[w][j] * wr[j];
        s_e[w][lane] = acc;
    }
    __syncthreads();

    if (lane < HID) {
        float acc = 0.f;
        const float* wr = g1w1 + lane * EMB;
        #pragma unroll
        for (int j = 0; j < EMB; ++j)
            acc += s_e[w][j] * wr[j];
        p1[(size_t)node * HID + lane] = acc;
    }
}

__global__ __launch_bounds__(256) void k_scatter(
    const float* __restrict__ p, const int* __restrict__ ei,
    float* __restrict__ agg)
{
    long long t = (long long)blockIdx.x * 256 + threadIdx.x;
    int e = (int)(t >> 4);
    int k = (int)(t & 15);
    if (e >= NE) return;
    int src = ei[e];
    int dst = ei[NE + e];
    float v = p[(size_t)src * HID + k];
    atomicAdd(agg + (size_t)dst * HID + k, v);
}

// ===========================================================================
// Shared MLP / readout kernels
// ===========================================================================
__global__ __launch_bounds__(256) void k_mlp1(
    const float* __restrict__ p1, const float* __restrict__ agg,
    const float* __restrict__ b1, const float* __restrict__ w2,
    const float* __restrict__ b2, const float* __restrict__ w3,
    float* __restrict__ p2)
{
    __shared__ float s_w2[HID * HID], s_w3[HID * HID], s_b1[HID], s_b2[HID];
    int tid = threadIdx.x;
    s_w2[tid] = w2[tid];
    s_w3[tid] = w3[tid];
    if (tid < HID) { s_b1[tid] = b1[tid]; s_b2[tid] = b2[tid]; }
    __syncthreads();

    int n = blockIdx.x * 256 + tid;
    if (n >= NN) return;

    float t[HID], h[HID];
    const float4* pa = (const float4*)(p1  + (size_t)n * HID);
    const float4* pb = (const float4*)(agg + (size_t)n * HID);
    #pragma unroll
    for (int i = 0; i < 4; ++i) {
        float4 a = pa[i], b = pb[i];
        t[i*4+0] = fmaxf(a.x + b.x + s_b1[i*4+0], 0.f);
        t[i*4+1] = fmaxf(a.y + b.y + s_b1[i*4+1], 0.f);
        t[i*4+2] = fmaxf(a.z + b.z + s_b1[i*4+2], 0.f);
        t[i*4+3] = fmaxf(a.w + b.w + s_b1[i*4+3], 0.f);
    }
    #pragma unroll
    for (int i = 0; i < HID; ++i) {
        float acc = s_b2[i];
        #pragma unroll
        for (int j = 0; j < HID; ++j) acc += t[j] * s_w2[i * HID + j];
        h[i] = fmaxf(acc, 0.f);
    }
    float o[HID];
    #pragma unroll
    for (int i = 0; i < HID; ++i) {
        float acc = 0.f;
        #pragma unroll
        for (int j = 0; j < HID; ++j) acc += h[j] * s_w3[i * HID + j];
        o[i] = acc;
    }
    float4* po = (float4*)(p2 + (size_t)n * HID);
    #pragma unroll
    for (int i = 0; i < 4; ++i)
        po[i] = make_float4(o[i*4+0], o[i*4+1], o[i*4+2], o[i*4+3]);
}

__global__ __launch_bounds__(256) void k_final(
    const float* __restrict__ p2, const float* __restrict__ agg2,
    const float* __restrict__ b1, const float* __restrict__ w2,
    const float* __restrict__ b2, const float* __restrict__ row,
    const float* __restrict__ rob,
    float* __restrict__ out)
{
    __shared__ float s_w2[HID * HID], s_b1[HID], s_b2[HID], s_ro[HID];
    int tid = threadIdx.x;
    s_w2[tid] = w2[tid];
    if (tid < HID) { s_b1[tid] = b1[tid]; s_b2[tid] = b2[tid]; s_ro[tid] = row[tid]; }
    __syncthreads();

    int n = blockIdx.x * 256 + tid;
    if (n >= NN) return;

    float t[HID];
    const float4* pa = (const float4*)(p2   + (size_t)n * HID);
    const float4* pb = (const float4*)(agg2 + (size_t)n * HID);
    #pragma unroll
    for (int i = 0; i < 4; ++i) {
        float4 a = pa[i], b = pb[i];
        t[i*4+0] = fmaxf(a.x + b.x + s_b1[i*4+0], 0.f);
        t[i*4+1] = fmaxf(a.y + b.y + s_b1[i*4+1], 0.f);
        t[i*4+2] = fmaxf(a.z + b.z + s_b1[i*4+2], 0.f);
        t[i*4+3] = fmaxf(a.w + b.w + s_b1[i*4+3], 0.f);
    }
    float res = rob[0];
    #pragma unroll
    for (int i = 0; i < HID; ++i) {
        float acc = s_b2[i];
        #pragma unroll
        for (int j = 0; j < HID; ++j) acc += t[j] * s_w2[i * HID + j];
        res += acc * s_ro[i];
    }
    out[n] = res;
}

// ===========================================================================
extern "C" void kernel_launch(void* const* d_in, const int* in_sizes, int n_in,
                              void* d_out, int out_size, void* d_ws, size_t ws_size,
                              hipStream_t stream)
{
    const float* x      = (const float*)d_in[0];
    const int*   ei     = (const int*)  d_in[1];
    const float* conv_w = (const float*)d_in[2];
    const float* conv_b = (const float*)d_in[3];
    const float* fc_w   = (const float*)d_in[4];
    const float* fc_b   = (const float*)d_in[5];
    const float* g1w1   = (const float*)d_in[6];
    const float* g1b1   = (const float*)d_in[7];
    const float* g1w2   = (const float*)d_in[8];
    const float* g1b2   = (const float*)d_in[9];
    const float* g2w1   = (const float*)d_in[10];
    const float* g2b1   = (const float*)d_in[11];
    const float* g2w2   = (const float*)d_in[12];
    const float* g2b2   = (const float*)d_in[13];
    const float* ro_w   = (const float*)d_in[14];
    const float* ro_b   = (const float*)d_in[15];
    float* out = (float*)d_out;

    // workspace layout:
    //   A   [NN*HID] f32    projected features
    //   B   [NN*HID] f32    aggregation buffer
    //   wcT [FLAT*HID] f32  combined fc+g1w1 weight, j-major
    //   bc  [16] f32        combined bias
    //   deg [NN] i32, off [NN+1] i32, cur [NN] i32, psum [512] i32
    //   csr [NE] i32        sources bucketed by destination
    float* A    = (float*)d_ws;
    float* B    = A + (size_t)NN * HID;
    float* wcT  = B + (size_t)NN * HID;
    float* bc   = wcT + (size_t)FLAT * HID;
    int*   deg  = (int*)(bc + 16);
    int*   off  = deg + NN;
    int*   cur  = off + NN + 1;
    int*   psum = cur + NN;
    int*   csr  = psum + 512;
    const size_t need = (size_t)((char*)(csr + NE) - (char*)d_ws);

    if (ws_size >= need) {
        // --- embed ---
        k_prep<<<1, 256, 0, stream>>>(g1w1, fc_w, fc_b, wcT, bc);
        k_convfc<<<NN / 32, 256, 0, stream>>>(x, conv_w, conv_b, wcT, bc, A);

        // --- CSR build (once; reused by both layers) ---
        hipMemsetAsync(deg, 0, (size_t)NN * sizeof(int), stream);
        k_hist<<<NE / 256, 256, 0, stream>>>(ei, deg);
        k_scan1<<<NB_SCAN, 256, 0, stream>>>(deg, off, psum);
        k_scan2<<<1, 512, 0, stream>>>(psum, off);
        k_scan3<<<NB_SCAN, 256, 0, stream>>>(off, psum, cur);
        k_fill<<<NE / 256, 256, 0, stream>>>(ei, cur, csr);

        // --- GIN layer 1: atomic-free gather ---
        k_gather<<<(NN * 4 + 255) / 256, 256, 0, stream>>>(A, off, csr, B);
        k_mlp1<<<(NN + 255) / 256, 256, 0, stream>>>(A, B, g1b1, g1w2, g1b2,
                                                     g2w1, A);
        // --- GIN layer 2 ---
        k_gather<<<(NN * 4 + 255) / 256, 256, 0, stream>>>(A, off, csr, B);
        k_final<<<(NN + 255) / 256, 256, 0, stream>>>(A, B, g2b1, g2w2, g2b2,
                                                      ro_w, ro_b, out);
    } else {
        // --- fallback: fused per-node embed + atomic scatter ---
        k_embed<<<NN / 4, 256, 0, stream>>>(x, conv_w, conv_b, fc_w, fc_b,
                                            g1w1, A);
        hipMemsetAsync(B, 0, (size_t)NN * HID * sizeof(float), stream);
        k_scatter<<<(int)(((long long)NE * HID) / 256), 256, 0, stream>>>(A, ei, B);
        k_mlp1<<<(NN + 255) / 256, 256, 0, stream>>>(A, B, g1b1, g1w2, g1b2,
                                                     g2w1, A);
        hipMemsetAsync(B, 0, (size_t)NN * HID * sizeof(float), stream);
        k_scatter<<<(int)(((long long)NE * HID) / 256), 256, 0, stream>>>(A, ei, B);
        k_final<<<(NN + 255) / 256, 256, 0, stream>>>(A, B, g2b1, g2w2, g2b2,
                                                      ro_w, ro_b, out);
    }
}

// Round 2
// 618.076 us; speedup vs baseline: 1.1507x; 1.1507x over previous
//
#include <hip/hip_runtime.h>

#define NN   100000
#define TL   128
#define OC   5
#define KW   7
#define ST   3
#define CL   41          // (128-7)/3+1
#define FLAT 205         // 5*41
#define EMB  32
#define HID  16
#define NE   3200000
#define NPART 8          // one partition per XCD
#define NEP  (NE / NPART)        // 400000 edges per partition
#define NTOT (NPART * NN)        // 800000 scan elements
#define NB1  (NTOT / 256)        // 3125, exact
#define FILL_GRID 2048           // 256 blocks per partition

// ===========================================================================
// Precompute combined weight Wc = g1w1 @ fc_w  ([16 x 205], stored transposed
// j-major as wcT[j*16+l]) and bc = g1w1 @ fc_b ([16]).  One block, trivial.
// ===========================================================================
__global__ __launch_bounds__(256) void k_prep(
    const float* __restrict__ g1w1, const float* __restrict__ fc_w,
    const float* __restrict__ fc_b,
    float* __restrict__ wcT, float* __restrict__ bc)
{
    int tid = threadIdx.x;
    for (int idx = tid; idx < FLAT * HID; idx += 256) {
        int l = idx & 15;
        int j = idx >> 4;
        float s = 0.f;
        #pragma unroll
        for (int m = 0; m < EMB; ++m)
            s = fmaf(g1w1[l * EMB + m], fc_w[m * FLAT + j], s);
        wcT[j * HID + l] = s;
    }
    if (tid < HID) {
        float s = 0.f;
        #pragma unroll
        for (int m = 0; m < EMB; ++m)
            s = fmaf(g1w1[tid * EMB + m], fc_b[m], s);
        bc[tid] = s;
    }
}

// ===========================================================================
// Fused Conv1d+ReLU+FC(+g1w1): 32-node tile per block.
// LDS = 32*129*4 + 205*32*4 = 42.75 KB -> 3 blocks/CU.  All LDS accesses
// 2-way-or-broadcast (free on CDNA4).
// ===========================================================================
__global__ __launch_bounds__(256) void k_convfc(
    const float* __restrict__ x,
    const float* __restrict__ conv_w, const float* __restrict__ conv_b,
    const float* __restrict__ wcT,   const float* __restrict__ bc,
    float* __restrict__ p1)
{
    __shared__ float s_x[32 * 129];
    __shared__ float s_h[FLAT * 32];
    const int tid = threadIdx.x;
    const long long n0 = (long long)blockIdx.x * 32;   // NN = 32*3125 exact

    const float4* xv = (const float4*)(x + n0 * TL);
    #pragma unroll
    for (int c = 0; c < 4; ++c) {
        int f4  = c * 256 + tid;      // 0..1023
        int row = f4 >> 5;
        int c4  = f4 & 31;
        float4 v = xv[f4];
        float* d = s_x + row * 129 + c4 * 4;
        d[0] = v.x; d[1] = v.y; d[2] = v.z; d[3] = v.w;
    }
    __syncthreads();

    for (int idx = tid; idx < FLAT * 32; idx += 256) {
        int n = idx & 31;
        int o = idx >> 5;
        int c = o / CL;
        int t = o - c * CL;
        float acc = conv_b[c];
        const float* wr = conv_w + c * KW;
        const float* xr = s_x + n * 129 + t * ST;
        #pragma unroll
        for (int k = 0; k < KW; ++k)
            acc = fmaf(xr[k], wr[k], acc);
        s_h[o * 32 + n] = fmaxf(acc, 0.f);
    }
    __syncthreads();

    const int l  = tid & 15;
    const int n2 = tid >> 4;
    float a0 = bc[l];
    float a1 = a0;
    #pragma unroll 5
    for (int j = 0; j < FLAT; ++j) {
        float w = wcT[j * HID + l];
        a0 = fmaf(s_h[j * 32 + n2],      w, a0);
        a1 = fmaf(s_h[j * 32 + n2 + 16], w, a1);
    }
    p1[(n0 + n2)      * HID + l] = a0;
    p1[(n0 + n2 + 16) * HID + l] = a1;
}

// ===========================================================================
// XCD-partitioned CSR build.  Partition p = blockIdx%8 -> XCD p (round-robin
// dispatch heuristic).  Each partition owns a private cursor array (400 KB)
// and contiguous csr region (1.6 MB) -> fits that XCD's 4 MB L2, no
// cross-XCD false sharing, stores coalesce into full lines in L2.
// ===========================================================================
__global__ __launch_bounds__(256) void k_hist8(
    const int* __restrict__ ei, int* __restrict__ deg8)
{
    const int b  = blockIdx.x;            // 0..FILL_GRID-1
    const int p  = b & 7;
    const int lt = (b >> 3) * 256 + threadIdx.x;   // 0..65535
    const int base = p * NEP;
    int* dp = deg8 + p * NN;
    for (int e = lt; e < NEP; e += (FILL_GRID / NPART) * 256)
        atomicAdd(dp + ei[NE + base + e], 1);
}

__global__ __launch_bounds__(256) void k_fill8(
    const int* __restrict__ ei, int* __restrict__ cur8,
    int* __restrict__ csr)
{
    const int b  = blockIdx.x;
    const int p  = b & 7;
    const int lt = (b >> 3) * 256 + threadIdx.x;
    const int base = p * NEP;
    int* cp = cur8 + p * NN;
    for (int e = lt; e < NEP; e += (FILL_GRID / NPART) * 256) {
        int src = ei[base + e];
        int dst = ei[NE + base + e];
        int pos = atomicAdd(cp + dst, 1);
        csr[pos] = src;
    }
}

// ---------------------------------------------------------------------------
// Exclusive scan over deg8[NTOT] -> off8 (partition-major: idx = p*NN+node).
// Partition regions in csr are automatically contiguous (each has exactly
// NEP edges), so off8[i+1] is always the correct run end; off8[NTOT] = NE.
// ---------------------------------------------------------------------------
__global__ __launch_bounds__(256) void k_scan1(
    const int* __restrict__ deg, int* __restrict__ off,
    int* __restrict__ psum)
{
    __shared__ int s[256];
    int i = blockIdx.x * 256 + threadIdx.x;       // NTOT exact multiple of 256
    int v = deg[i];
    s[threadIdx.x] = v;
    __syncthreads();
    #pragma unroll
    for (int d = 1; d < 256; d <<= 1) {
        int t = (threadIdx.x >= d) ? s[threadIdx.x - d] : 0;
        __syncthreads();
        s[threadIdx.x] += t;
        __syncthreads();
    }
    off[i] = s[threadIdx.x] - v;                  // exclusive (local)
    if (threadIdx.x == 255) psum[blockIdx.x] = s[255];
}

__global__ __launch_bounds__(1024) void k_scan2(
    int* __restrict__ psum, int* __restrict__ off)
{
    __shared__ int s[1024];
    const int tid = threadIdx.x;
    int v[4];
    int tot = 0;
    #pragma unroll
    for (int i = 0; i < 4; ++i) {
        int idx = tid * 4 + i;
        v[i] = (idx < NB1) ? psum[idx] : 0;
        tot += v[i];
    }
    s[tid] = tot;
    __syncthreads();
    #pragma unroll
    for (int d = 1; d < 1024; d <<= 1) {
        int t = (tid >= d) ? s[tid - d] : 0;
        __syncthreads();
        s[tid] += t;
        __syncthreads();
    }
    int run = s[tid] - tot;                       // exclusive base
    #pragma unroll
    for (int i = 0; i < 4; ++i) {
        int idx = tid * 4 + i;
        if (idx < NB1) psum[idx] = run;
        run += v[i];
    }
    if (tid == 0) off[NTOT] = NE;                 // sentinel
}

__global__ __launch_bounds__(256) void k_scan3(
    int* __restrict__ off, const int* __restrict__ psum,
    int* __restrict__ cur)
{
    int i = blockIdx.x * 256 + threadIdx.x;
    int v = off[i] + psum[blockIdx.x];
    off[i] = v;
    cur[i] = v;
}

// ===========================================================================
// Atomic-free aggregation: 4 lanes per node, float4 per lane; per node walk
// the 8 per-partition runs (contiguity makes off8[i+1] the run end).
// ===========================================================================
__global__ __launch_bounds__(256) void k_gather8(
    const float* __restrict__ pfeat, const int* __restrict__ off8,
    const int* __restrict__ csr, float* __restrict__ agg)
{
    const int t  = blockIdx.x * 256 + threadIdx.x;
    const int g  = t >> 2;
    const int l4 = t & 3;
    if (g >= NN) return;
    const float4* pv = (const float4*)pfeat;
    float4 acc = make_float4(0.f, 0.f, 0.f, 0.f);
    #pragma unroll
    for (int p = 0; p < NPART; ++p) {
        int j = off8[p * NN + g];
        const int e = off8[p * NN + g + 1];
        for (; j + 1 < e; j += 2) {
            int s0 = csr[j], s1 = csr[j + 1];
            float4 a = pv[(size_t)s0 * 4 + l4];
            float4 b = pv[(size_t)s1 * 4 + l4];
            acc.x += a.x + b.x; acc.y += a.y + b.y;
            acc.z += a.z + b.z; acc.w += a.w + b.w;
        }
        if (j < e) {
            float4 a = pv[(size_t)csr[j] * 4 + l4];
            acc.x += a.x; acc.y += a.y; acc.z += a.z; acc.w += a.w;
        }
    }
    ((float4*)agg)[(size_t)g * 4 + l4] = acc;
}

// ===========================================================================
// FALLBACK PATH kernels (workspace too small): per-node embed + atomic scatter
// ===========================================================================
__global__ __launch_bounds__(256) void k_embed(
    const float* __restrict__ x,
    const float* __restrict__ conv_w, const float* __restrict__ conv_b,
    const float* __restrict__ fc_w,   const float* __restrict__ fc_b,
    const float* __restrict__ g1w1,
    float* __restrict__ p1)
{
    __shared__ float s_x[4][TL];
    __shared__ float s_h[4][FLAT + 3];
    __shared__ float s_e[4][EMB];

    const int w    = threadIdx.x >> 6;
    const int lane = threadIdx.x & 63;
    const int node = blockIdx.x * 4 + w;

    const float2* xr = (const float2*)(x + (size_t)node * TL);
    float2 v = xr[lane];
    s_x[w][lane * 2 + 0] = v.x;
    s_x[w][lane * 2 + 1] = v.y;
    __syncthreads();

    for (int o = lane; o < FLAT; o += 64) {
        int c = o / CL;
        int t = o - c * CL;
        float acc = conv_b[c];
        #pragma unroll
        for (int k = 0; k < KW; ++k)
            acc += s_x[w][t * ST + k] * conv_w[c * KW + k];
        s_h[w][o] = fmaxf(acc, 0.f);
    }
    __syncthreads();

    if (lane < EMB) {
        float acc = fc_b[lane];
        const float* wr = fc_w + lane * FLAT;
        for (int j = 0; j < FLAT; ++j)
            acc += s_h[w][j] * wr[j];
        s_e[w][lane] = acc;
    }
    __syncthreads();

    if (lane < HID) {
        float acc = 0.f;
        const float* wr = g1w1 + lane * EMB;
        #pragma unroll
        for (int j = 0; j < EMB; ++j)
            acc += s_e[w][j] * wr[j];
        p1[(size_t)node * HID + lane] = acc;
    }
}

__global__ __launch_bounds__(256) void k_scatter(
    const float* __restrict__ p, const int* __restrict__ ei,
    float* __restrict__ agg)
{
    long long t = (long long)blockIdx.x * 256 + threadIdx.x;
    int e = (int)(t >> 4);
    int k = (int)(t & 15);
    if (e >= NE) return;
    int src = ei[e];
    int dst = ei[NE + e];
    float v = p[(size_t)src * HID + k];
    atomicAdd(agg + (size_t)dst * HID + k, v);
}

// ===========================================================================
// Shared MLP / readout kernels
// ===========================================================================
__global__ __launch_bounds__(256) void k_mlp1(
    const float* __restrict__ p1, const float* __restrict__ agg,
    const float* __restrict__ b1, const float* __restrict__ w2,
    const float* __restrict__ b2, const float* __restrict__ w3,
    float* __restrict__ p2)
{
    __shared__ float s_w2[HID * HID], s_w3[HID * HID], s_b1[HID], s_b2[HID];
    int tid = threadIdx.x;
    s_w2[tid] = w2[tid];
    s_w3[tid] = w3[tid];
    if (tid < HID) { s_b1[tid] = b1[tid]; s_b2[tid] = b2[tid]; }
    __syncthreads();

    int n = blockIdx.x * 256 + tid;
    if (n >= NN) return;

    float t[HID], h[HID];
    const float4* pa = (const float4*)(p1  + (size_t)n * HID);
    const float4* pb = (const float4*)(agg + (size_t)n * HID);
    #pragma unroll
    for (int i = 0; i < 4; ++i) {
        float4 a = pa[i], b = pb[i];
        t[i*4+0] = fmaxf(a.x + b.x + s_b1[i*4+0], 0.f);
        t[i*4+1] = fmaxf(a.y + b.y + s_b1[i*4+1], 0.f);
        t[i*4+2] = fmaxf(a.z + b.z + s_b1[i*4+2], 0.f);
        t[i*4+3] = fmaxf(a.w + b.w + s_b1[i*4+3], 0.f);
    }
    #pragma unroll
    for (int i = 0; i < HID; ++i) {
        float acc = s_b2[i];
        #pragma unroll
        for (int j = 0; j < HID; ++j) acc += t[j] * s_w2[i * HID + j];
        h[i] = fmaxf(acc, 0.f);
    }
    float o[HID];
    #pragma unroll
    for (int i = 0; i < HID; ++i) {
        float acc = 0.f;
        #pragma unroll
        for (int j = 0; j < HID; ++j) acc += h[j] * s_w3[i * HID + j];
        o[i] = acc;
    }
    float4* po = (float4*)(p2 + (size_t)n * HID);
    #pragma unroll
    for (int i = 0; i < 4; ++i)
        po[i] = make_float4(o[i*4+0], o[i*4+1], o[i*4+2], o[i*4+3]);
}

__global__ __launch_bounds__(256) void k_final(
    const float* __restrict__ p2, const float* __restrict__ agg2,
    const float* __restrict__ b1, const float* __restrict__ w2,
    const float* __restrict__ b2, const float* __restrict__ row,
    const float* __restrict__ rob,
    float* __restrict__ out)
{
    __shared__ float s_w2[HID * HID], s_b1[HID], s_b2[HID], s_ro[HID];
    int tid = threadIdx.x;
    s_w2[tid] = w2[tid];
    if (tid < HID) { s_b1[tid] = b1[tid]; s_b2[tid] = b2[tid]; s_ro[tid] = row[tid]; }
    __syncthreads();

    int n = blockIdx.x * 256 + tid;
    if (n >= NN) return;

    float t[HID];
    const float4* pa = (const float4*)(p2   + (size_t)n * HID);
    const float4* pb = (const float4*)(agg2 + (size_t)n * HID);
    #pragma unroll
    for (int i = 0; i < 4; ++i) {
        float4 a = pa[i], b = pb[i];
        t[i*4+0] = fmaxf(a.x + b.x + s_b1[i*4+0], 0.f);
        t[i*4+1] = fmaxf(a.y + b.y + s_b1[i*4+1], 0.f);
        t[i*4+2] = fmaxf(a.z + b.z + s_b1[i*4+2], 0.f);
        t[i*4+3] = fmaxf(a.w + b.w + s_b1[i*4+3], 0.f);
    }
    float res = rob[0];
    #pragma unroll
    for (int i = 0; i < HID; ++i) {
        float acc = s_b2[i];
        #pragma unroll
        for (int j = 0; j < HID; ++j) acc += t[j] * s_w2[i * HID + j];
        res += acc * s_ro[i];
    }
    out[n] = res;
}

// ===========================================================================
extern "C" void kernel_launch(void* const* d_in, const int* in_sizes, int n_in,
                              void* d_out, int out_size, void* d_ws, size_t ws_size,
                              hipStream_t stream)
{
    const float* x      = (const float*)d_in[0];
    const int*   ei     = (const int*)  d_in[1];
    const float* conv_w = (const float*)d_in[2];
    const float* conv_b = (const float*)d_in[3];
    const float* fc_w   = (const float*)d_in[4];
    const float* fc_b   = (const float*)d_in[5];
    const float* g1w1   = (const float*)d_in[6];
    const float* g1b1   = (const float*)d_in[7];
    const float* g1w2   = (const float*)d_in[8];
    const float* g1b2   = (const float*)d_in[9];
    const float* g2w1   = (const float*)d_in[10];
    const float* g2b1   = (const float*)d_in[11];
    const float* g2w2   = (const float*)d_in[12];
    const float* g2b2   = (const float*)d_in[13];
    const float* ro_w   = (const float*)d_in[14];
    const float* ro_b   = (const float*)d_in[15];
    float* out = (float*)d_out;

    // workspace layout:
    //   A    [NN*HID] f32     projected features
    //   B    [NN*HID] f32     aggregation buffer
    //   wcT  [FLAT*HID] f32   combined fc+g1w1 weight, j-major
    //   bc   [16] f32         combined bias
    //   deg8 [NTOT] i32       per-partition per-node degree
    //   off8 [NTOT+1] i32     per-partition CSR offsets (partition-major)
    //   cur8 [NTOT] i32       fill cursors
    //   psum [NB1] i32        scan block sums
    //   csr  [NE] i32         sources, partition-major then dst-ordered
    float* A    = (float*)d_ws;
    float* B    = A + (size_t)NN * HID;
    float* wcT  = B + (size_t)NN * HID;
    float* bc   = wcT + (size_t)FLAT * HID;
    int*   deg8 = (int*)(bc + 16);
    int*   off8 = deg8 + NTOT;
    int*   cur8 = off8 + NTOT + 1;
    int*   psum = cur8 + NTOT;
    int*   csr  = psum + NB1;
    const size_t need = (size_t)((char*)(csr + NE) - (char*)d_ws);

    if (ws_size >= need) {
        // --- embed ---
        k_prep<<<1, 256, 0, stream>>>(g1w1, fc_w, fc_b, wcT, bc);
        k_convfc<<<NN / 32, 256, 0, stream>>>(x, conv_w, conv_b, wcT, bc, A);

        // --- XCD-partitioned CSR build (once; reused by both layers) ---
        hipMemsetAsync(deg8, 0, (size_t)NTOT * sizeof(int), stream);
        k_hist8<<<FILL_GRID, 256, 0, stream>>>(ei, deg8);
        k_scan1<<<NB1, 256, 0, stream>>>(deg8, off8, psum);
        k_scan2<<<1, 1024, 0, stream>>>(psum, off8);
        k_scan3<<<NB1, 256, 0, stream>>>(off8, psum, cur8);
        k_fill8<<<FILL_GRID, 256, 0, stream>>>(ei, cur8, csr);

        // --- GIN layer 1: atomic-free gather ---
        k_gather8<<<(NN * 4 + 255) / 256, 256, 0, stream>>>(A, off8, csr, B);
        k_mlp1<<<(NN + 255) / 256, 256, 0, stream>>>(A, B, g1b1, g1w2, g1b2,
                                                     g2w1, A);
        // --- GIN layer 2 ---
        k_gather8<<<(NN * 4 + 255) / 256, 256, 0, stream>>>(A, off8, csr, B);
        k_final<<<(NN + 255) / 256, 256, 0, stream>>>(A, B, g2b1, g2w2, g2b2,
                                                      ro_w, ro_b, out);
    } else {
        // --- fallback: fused per-node embed + atomic scatter ---
        k_embed<<<NN / 4, 256, 0, stream>>>(x, conv_w, conv_b, fc_w, fc_b,
                                            g1w1, A);
        hipMemsetAsync(B, 0, (size_t)NN * HID * sizeof(float), stream);
        k_scatter<<<(int)(((long long)NE * HID) / 256), 256, 0, stream>>>(A, ei, B);
        k_mlp1<<<(NN + 255) / 256, 256, 0, stream>>>(A, B, g1b1, g1w2, g1b2,
                                                     g2w1, A);
        hipMemsetAsync(B, 0, (size_t)NN * HID * sizeof(float), stream);
        k_scatter<<<(int)(((long long)NE * HID) / 256), 256, 0, stream>>>(A, ei, B);
        k_final<<<(NN + 255) / 256, 256, 0, stream>>>(A, B, g2b1, g2w2, g2b2,
                                                      ro_w, ro_b, out);
    }
}